// Round 3
// baseline (120.729 us; speedup 1.0000x reference)
//
#include <hip/hip_runtime.h>

#define HW_PIX (512 * 512)
#define NUM_CLASSES 4
#define IGNORE_INDEX 4

__global__ __launch_bounds__(256) void ce_main_kernel(
    const float* __restrict__ pred,
    const int* __restrict__ target,
    const int* __restrict__ me,
    float* __restrict__ partials,   // [gridDim.x * 2]
    int n_groups) {
  float lsum = 0.0f;
  float lcnt = 0.0f;

  int g = blockIdx.x * blockDim.x + threadIdx.x;   // one 4-pixel group per thread
  if (g < n_groups) {
    int pg = g << 2;               // first pixel of this group
    int b = pg >> 18;              // / (512*512)
    int p = pg & (HW_PIX - 1);     // % (512*512)

    const float* base = pred + (size_t)b * NUM_CLASSES * HW_PIX + p;
    float4 c0 = *reinterpret_cast<const float4*>(base);
    float4 c1 = *reinterpret_cast<const float4*>(base + HW_PIX);
    float4 c2 = *reinterpret_cast<const float4*>(base + 2 * HW_PIX);
    float4 c3 = *reinterpret_cast<const float4*>(base + 3 * HW_PIX);

    const size_t tbase = (size_t)b * HW_PIX + p;
    int4 tg = *reinterpret_cast<const int4*>(target + tbase);
    int4 mg = *reinterpret_cast<const int4*>(me + tbase);

#define DO_PIXEL(X0, X1, X2, X3, T, M)                                     \
    do {                                                                   \
      int t_ = (T);                                                        \
      if (t_ != IGNORE_INDEX) {                                            \
        float m_ = fmaxf(fmaxf((X0), (X1)), fmaxf((X2), (X3)));            \
        float e_ = __expf((X0) - m_) + __expf((X1) - m_) +                 \
                   __expf((X2) - m_) + __expf((X3) - m_);                  \
        float lse_ = m_ + __logf(e_);                                      \
        float xt_ = (t_ == 0) ? (X0) : (t_ == 1) ? (X1)                    \
                  : (t_ == 2) ? (X2) : (X3);                               \
        float w_ = ((M) == 0) ? 1.0f : 0.5f;                               \
        lsum += w_ * (lse_ - xt_);                                         \
        lcnt += 1.0f;                                                      \
      }                                                                    \
    } while (0)

    DO_PIXEL(c0.x, c1.x, c2.x, c3.x, tg.x, mg.x);
    DO_PIXEL(c0.y, c1.y, c2.y, c3.y, tg.y, mg.y);
    DO_PIXEL(c0.z, c1.z, c2.z, c3.z, tg.z, mg.z);
    DO_PIXEL(c0.w, c1.w, c2.w, c3.w, tg.w, mg.w);
#undef DO_PIXEL
  }

  // wave-64 butterfly reduce
  for (int off = 32; off > 0; off >>= 1) {
    lsum += __shfl_down(lsum, off, 64);
    lcnt += __shfl_down(lcnt, off, 64);
  }

  __shared__ float s_sum[4];
  __shared__ float s_cnt[4];
  int wid = threadIdx.x >> 6;
  int lane = threadIdx.x & 63;
  if (lane == 0) {
    s_sum[wid] = lsum;
    s_cnt[wid] = lcnt;
  }
  __syncthreads();

  if (threadIdx.x == 0) {
    float ts = s_sum[0] + s_sum[1] + s_sum[2] + s_sum[3];
    float tc = s_cnt[0] + s_cnt[1] + s_cnt[2] + s_cnt[3];
    partials[2 * blockIdx.x] = ts;       // plain store — no atomics
    partials[2 * blockIdx.x + 1] = tc;
  }
}

__global__ __launch_bounds__(256) void ce_final_kernel(
    const float* __restrict__ partials, float* __restrict__ out, int nblocks) {
  float lsum = 0.0f;
  float lcnt = 0.0f;
  const float2* p2 = reinterpret_cast<const float2*>(partials);
  for (int j = threadIdx.x; j < nblocks; j += 256) {
    float2 v = p2[j];
    lsum += v.x;
    lcnt += v.y;
  }
  for (int off = 32; off > 0; off >>= 1) {
    lsum += __shfl_down(lsum, off, 64);
    lcnt += __shfl_down(lcnt, off, 64);
  }
  __shared__ float s_sum[4];
  __shared__ float s_cnt[4];
  int wid = threadIdx.x >> 6;
  int lane = threadIdx.x & 63;
  if (lane == 0) {
    s_sum[wid] = lsum;
    s_cnt[wid] = lcnt;
  }
  __syncthreads();
  if (threadIdx.x == 0) {
    float ts = s_sum[0] + s_sum[1] + s_sum[2] + s_sum[3];
    float tc = s_cnt[0] + s_cnt[1] + s_cnt[2] + s_cnt[3];
    out[0] = ts / tc;
  }
}

extern "C" void kernel_launch(void* const* d_in, const int* in_sizes, int n_in,
                              void* d_out, int out_size, void* d_ws, size_t ws_size,
                              hipStream_t stream) {
  const float* pred = (const float*)d_in[0];
  const int* target = (const int*)d_in[1];
  const int* me = (const int*)d_in[2];
  float* partials = (float*)d_ws;   // every slot rewritten each launch; no memset needed
  float* out = (float*)d_out;

  int total_pixels = in_sizes[1];       // B*H*W = 4,194,304
  int n_groups = total_pixels >> 2;     // 1,048,576 groups, one per thread
  int block = 256;
  int grid = (n_groups + block - 1) / block;   // 4096 blocks

  ce_main_kernel<<<grid, block, 0, stream>>>(pred, target, me, partials, n_groups);
  ce_final_kernel<<<1, 256, 0, stream>>>(partials, out, grid);
}

// Round 9
// 119.215 us; speedup vs baseline: 1.0127x; 1.0127x over previous
//
#include <hip/hip_runtime.h>

#define HW_PIX (512 * 512)
#define NUM_CLASSES 4
#define IGNORE_INDEX 4

__global__ __launch_bounds__(256) void ce_main_kernel(
    const float* __restrict__ pred,
    const int* __restrict__ target,
    const int* __restrict__ me,
    float* __restrict__ partials,   // [gridDim.x] float2
    int n_groups8) {
  float lsum = 0.0f;
  float lcnt = 0.0f;

  int g = blockIdx.x * blockDim.x + threadIdx.x;   // one 8-pixel group per thread
  if (g < n_groups8) {
    int pg = g << 3;               // first pixel of this group
    int b = pg >> 18;              // / (512*512)
    int p = pg & (HW_PIX - 1);     // % (512*512)  (8 | HW_PIX, no straddle)

    const float* base = pred + (size_t)b * NUM_CLASSES * HW_PIX + p;
    // issue all 12 16-B loads up front for max MLP
    float4 x00 = *reinterpret_cast<const float4*>(base);
    float4 x01 = *reinterpret_cast<const float4*>(base + 4);
    float4 x10 = *reinterpret_cast<const float4*>(base + HW_PIX);
    float4 x11 = *reinterpret_cast<const float4*>(base + HW_PIX + 4);
    float4 x20 = *reinterpret_cast<const float4*>(base + 2 * HW_PIX);
    float4 x21 = *reinterpret_cast<const float4*>(base + 2 * HW_PIX + 4);
    float4 x30 = *reinterpret_cast<const float4*>(base + 3 * HW_PIX);
    float4 x31 = *reinterpret_cast<const float4*>(base + 3 * HW_PIX + 4);

    const size_t tbase = (size_t)b * HW_PIX + p;
    int4 tg0 = *reinterpret_cast<const int4*>(target + tbase);
    int4 tg1 = *reinterpret_cast<const int4*>(target + tbase + 4);
    int4 mg0 = *reinterpret_cast<const int4*>(me + tbase);
    int4 mg1 = *reinterpret_cast<const int4*>(me + tbase + 4);

    // branchless per-pixel: always compute LSE, mask via selects
#define DO_PIXEL(X0, X1, X2, X3, T, M)                                     \
    do {                                                                   \
      int t_ = (T);                                                        \
      float m_ = fmaxf(fmaxf((X0), (X1)), fmaxf((X2), (X3)));              \
      float e_ = __expf((X0) - m_) + __expf((X1) - m_) +                   \
                 __expf((X2) - m_) + __expf((X3) - m_);                    \
      float lse_ = m_ + __logf(e_);                                        \
      float xt_ = (t_ == 0) ? (X0) : (t_ == 1) ? (X1)                      \
                : (t_ == 2) ? (X2) : (X3);                                 \
      float valid_ = (t_ != IGNORE_INDEX) ? 1.0f : 0.0f;                   \
      float w_ = ((M) == 0) ? 1.0f : 0.5f;                                 \
      lsum += valid_ * w_ * (lse_ - xt_);                                  \
      lcnt += valid_;                                                      \
    } while (0)

    DO_PIXEL(x00.x, x10.x, x20.x, x30.x, tg0.x, mg0.x);
    DO_PIXEL(x00.y, x10.y, x20.y, x30.y, tg0.y, mg0.y);
    DO_PIXEL(x00.z, x10.z, x20.z, x30.z, tg0.z, mg0.z);
    DO_PIXEL(x00.w, x10.w, x20.w, x30.w, tg0.w, mg0.w);
    DO_PIXEL(x01.x, x11.x, x21.x, x31.x, tg1.x, mg1.x);
    DO_PIXEL(x01.y, x11.y, x21.y, x31.y, tg1.y, mg1.y);
    DO_PIXEL(x01.z, x11.z, x21.z, x31.z, tg1.z, mg1.z);
    DO_PIXEL(x01.w, x11.w, x21.w, x31.w, tg1.w, mg1.w);
#undef DO_PIXEL
  }

  // wave-64 butterfly reduce
  for (int off = 32; off > 0; off >>= 1) {
    lsum += __shfl_down(lsum, off, 64);
    lcnt += __shfl_down(lcnt, off, 64);
  }

  __shared__ float s_sum[4];
  __shared__ float s_cnt[4];
  int wid = threadIdx.x >> 6;
  int lane = threadIdx.x & 63;
  if (lane == 0) {
    s_sum[wid] = lsum;
    s_cnt[wid] = lcnt;
  }
  __syncthreads();

  if (threadIdx.x == 0) {
    float2 v;
    v.x = s_sum[0] + s_sum[1] + s_sum[2] + s_sum[3];
    v.y = s_cnt[0] + s_cnt[1] + s_cnt[2] + s_cnt[3];
    reinterpret_cast<float2*>(partials)[blockIdx.x] = v;   // plain store — no atomics
  }
}

__global__ __launch_bounds__(256) void ce_final_kernel(
    const float* __restrict__ partials, float* __restrict__ out, int nblocks) {
  float lsum = 0.0f;
  float lcnt = 0.0f;
  const float2* p2 = reinterpret_cast<const float2*>(partials);
  for (int j = threadIdx.x; j < nblocks; j += 256) {
    float2 v = p2[j];
    lsum += v.x;
    lcnt += v.y;
  }
  for (int off = 32; off > 0; off >>= 1) {
    lsum += __shfl_down(lsum, off, 64);
    lcnt += __shfl_down(lcnt, off, 64);
  }
  __shared__ float s_sum[4];
  __shared__ float s_cnt[4];
  int wid = threadIdx.x >> 6;
  int lane = threadIdx.x & 63;
  if (lane == 0) {
    s_sum[wid] = lsum;
    s_cnt[wid] = lcnt;
  }
  __syncthreads();
  if (threadIdx.x == 0) {
    float ts = s_sum[0] + s_sum[1] + s_sum[2] + s_sum[3];
    float tc = s_cnt[0] + s_cnt[1] + s_cnt[2] + s_cnt[3];
    out[0] = ts / tc;
  }
}

extern "C" void kernel_launch(void* const* d_in, const int* in_sizes, int n_in,
                              void* d_out, int out_size, void* d_ws, size_t ws_size,
                              hipStream_t stream) {
  const float* pred = (const float*)d_in[0];
  const int* target = (const int*)d_in[1];
  const int* me = (const int*)d_in[2];
  float* partials = (float*)d_ws;   // every slot rewritten each launch; no memset needed
  float* out = (float*)d_out;

  int total_pixels = in_sizes[1];       // B*H*W = 4,194,304
  int n_groups8 = total_pixels >> 3;    // 524,288 8-pixel groups, one per thread
  int block = 256;
  int grid = (n_groups8 + block - 1) / block;   // 2048 blocks

  ce_main_kernel<<<grid, block, 0, stream>>>(pred, target, me, partials, n_groups8);
  ce_final_kernel<<<1, 256, 0, stream>>>(partials, out, grid);
}